// Round 8
// baseline (5607.150 us; speedup 1.0000x reference)
//
#include <hip/hip_runtime.h>

// Problem constants (B,S,D=16,2048,256; K codebooks=8, CD=1024)
#define DD    256
#define KST   8
#define CDN   1024
#define NROWS 32768          // B*S
#define ROWS  32             // rows (tokens) per block
#define NT    128            // codeword tile per sweep
#define KC    32             // k-chunk staged in LDS
#define AST   33             // a_t row stride (32+1 pad)
#define BST   68             // b_t col stride (64+4 pad)

__device__ __forceinline__ bool better(float a, int ja, float b, int jb_) {
    return (a < b) || (a == b && ja < jb_);
}

// ---------------------------------------------------------------------------
// numpy AVX512 pairwise sum-of-squares over 256 contiguous values (emulated):
// 256 -> two 128-blocks; each block: 8 vectors of 16 lanes v_j[l]=x[16j+l],
// per-lane tree ((v0+v1)+(v2+v3))+((v4+v5)+(v6+v7)), then _mm512_reduce_add:
// t8[l]=w[l]+w[l+8]; t4[l]=t8[l]+t8[l+4]; t2[l]=t4[l]+t4[l+2]; s=t2[0]+t2[1];
// total = fl(block0 + block1). All roundings explicit.
template <typename F>
__device__ __forceinline__ float np_sumsq_256(F ld) {
    float Sv = 0.f;
#pragma unroll
    for (int blk = 0; blk < 2; ++blk) {
        const int o = blk * 128;
        float w[16];
#pragma unroll
        for (int l = 0; l < 16; ++l) {
            float v[8];
#pragma unroll
            for (int j = 0; j < 8; ++j) {
                float xv = ld(o + 16 * j + l);
                v[j] = __fmul_rn(xv, xv);
            }
            float a01 = __fadd_rn(v[0], v[1]);
            float a23 = __fadd_rn(v[2], v[3]);
            float a45 = __fadd_rn(v[4], v[5]);
            float a67 = __fadd_rn(v[6], v[7]);
            w[l] = __fadd_rn(__fadd_rn(a01, a23), __fadd_rn(a45, a67));
        }
        float t8[8];
#pragma unroll
        for (int l = 0; l < 8; ++l) t8[l] = __fadd_rn(w[l], w[l + 8]);
        float t4[4];
#pragma unroll
        for (int l = 0; l < 4; ++l) t4[l] = __fadd_rn(t8[l], t8[l + 4]);
        float t2_0 = __fadd_rn(t4[0], t4[2]);
        float t2_1 = __fadd_rn(t4[1], t4[3]);
        float bs = __fadd_rn(t2_0, t2_1);
        Sv = (blk == 0) ? bs : __fadd_rn(Sv, bs);
    }
    return Sv;
}

// ---------------------------------------------------------------------------
// ||c_j||^2 with numpy-AVX512 rounding. One thread per codeword.
__global__ __launch_bounds__(256) void norms_kernel(const float* __restrict__ cb,
                                                    float* __restrict__ n32) {
    int j = blockIdx.x * 256 + threadIdx.x;   // 0..8191
    const float* p = cb + (size_t)j * DD;
    n32[j] = np_sumsq_256([&](int i) { return p[i]; });
}

// ---------------------------------------------------------------------------
// Fused RVQ — numpy-fp32 emulation with AVX512 reduction trees:
//   dot[j]  : sequential k-ascending FMA chain (single accumulator) == sgemm
//   S, C    : numpy AVX512 pairwise trees (emulated bit-wise)
//   d2[j]   : fl32(fl32(S - fl32(2*dot)) + C[j])
//   argmin  : lexicographic (d2, j) == np.argmin first-occurrence
__global__ __launch_bounds__(256) void rvq_kernel(const float* __restrict__ x,
                                                  const float* __restrict__ cbs,
                                                  const float* __restrict__ n32,
                                                  float* __restrict__ out) {
    __shared__ float a_t[DD][AST];        // residual, transposed: a_t[d][row]
    __shared__ float b_t[2][KC][BST];     // codeword tile halves
    __shared__ float rowS[ROWS];          // np-AVX512 sum(res*res) per row
    __shared__ int   rowidx[ROWS];        // winner per row
    __shared__ int   idxhist[KST][ROWS];
    __shared__ float wred[4];

    const int tid  = threadIdx.x;
    const int base = blockIdx.x * ROWS;
    const int tx   = tid & 15;            // GEMM col-group
    const int ty   = tid >> 4;            // GEMM row-group (2 rows)
    const int row0 = ty * 2;
    const int urow = tid >> 3;            // update row (8 thr/row)
    const int ug   = tid & 7;             // owned dims: ug + 8*i

    for (int i = tid; i < ROWS * DD / 4; i += 256) {
        int row = i >> 6;
        int dq  = i & 63;
        float4 v = ((const float4*)(x + (size_t)(base + row) * DD))[dq];
        int d = dq * 4;
        a_t[d + 0][row] = v.x; a_t[d + 1][row] = v.y;
        a_t[d + 2][row] = v.z; a_t[d + 3][row] = v.w;
    }

    float loss_acc = 0.f;

    for (int s = 0; s < KST; ++s) {
        const float* cb = cbs + (size_t)s * CDN * DD;
        const float* nr = n32 + s * CDN;
        __syncthreads();                  // a_t ready

        // np-AVX512 S = sum(res*res) per row; one thread per row
        if (tid < ROWS) {
            int row = tid;
            rowS[row] = np_sumsq_256([&](int i) { return a_t[i][row]; });
        }
        __syncthreads();

        // running best per handled row (held by tx==0 threads)
        float rb[2] = {3.4e38f, 3.4e38f};
        int   rjx[2] = {0x7ffffff, 0x7ffffff};

        for (int jb = 0; jb < CDN; jb += NT) {
            float acc[2][8];
#pragma unroll
            for (int r = 0; r < 2; ++r)
#pragma unroll
                for (int c = 0; c < 8; ++c) acc[r][c] = 0.f;

            for (int kk = 0; kk < DD; kk += KC) {
                __syncthreads();
#pragma unroll
                for (int it = 0; it < 4; ++it) {
                    int li  = tid + it * 256;
                    int col = li >> 3;
                    int g   = li & 7;
                    float4 v = *(const float4*)(cb + (size_t)(jb + col) * DD + kk + g * 4);
                    int h = col >> 6, cl = col & 63;
                    b_t[h][g * 4 + 0][cl] = v.x; b_t[h][g * 4 + 1][cl] = v.y;
                    b_t[h][g * 4 + 2][cl] = v.z; b_t[h][g * 4 + 3][cl] = v.w;
                }
                __syncthreads();
                // sequential k-ascending FMA chains (one acc per (row,col))
#pragma unroll
                for (int k = 0; k < KC; ++k) {
                    float a0 = a_t[kk + k][row0];
                    float a1 = a_t[kk + k][row0 + 1];
                    float b0[4], b1[4];
#pragma unroll
                    for (int c = 0; c < 4; ++c) {
                        b0[c] = b_t[0][k][tx * 4 + c];
                        b1[c] = b_t[1][k][tx * 4 + c];
                    }
#pragma unroll
                    for (int c = 0; c < 4; ++c) {
                        acc[0][c]     = __builtin_fmaf(a0, b0[c], acc[0][c]);
                        acc[0][4 + c] = __builtin_fmaf(a0, b1[c], acc[0][4 + c]);
                        acc[1][c]     = __builtin_fmaf(a1, b0[c], acc[1][c]);
                        acc[1][4 + c] = __builtin_fmaf(a1, b1[c], acc[1][4 + c]);
                    }
                }
            }
            // np-composed score + fused argmin over this 128-col tile
#pragma unroll
            for (int r = 0; r < 2; ++r) {
                float Srow = rowS[row0 + r];
                float t1 = 3.4e38f; int u1 = 0x7ffffff;
#pragma unroll
                for (int h = 0; h < 2; ++h)
#pragma unroll
                    for (int c = 0; c < 4; ++c) {
                        int j = jb + h * 64 + tx * 4 + c;
                        float m2 = __fmul_rn(2.f, acc[r][h * 4 + c]);
                        float sc = __fadd_rn(__fsub_rn(Srow, m2), nr[j]);
                        if (better(sc, j, t1, u1)) { t1 = sc; u1 = j; }
                    }
#pragma unroll
                for (int off = 8; off >= 1; off >>= 1) {
                    float ob = __shfl_xor(t1, off, 16);
                    int   oj = __shfl_xor(u1, off, 16);
                    if (better(ob, oj, t1, u1)) { t1 = ob; u1 = oj; }
                }
                if (tx == 0 && better(t1, u1, rb[r], rjx[r])) { rb[r] = t1; rjx[r] = u1; }
            }
        }
        if (tx == 0) {
#pragma unroll
            for (int r = 0; r < 2; ++r) {
                rowidx[row0 + r] = rjx[r];
                idxhist[s][row0 + r] = rjx[r];
            }
        }
        __syncthreads();

        // residual update + loss (elementwise fp32, np-identical given picks)
        {
            int bi = rowidx[urow];
            const float4* cp = (const float4*)(cb + (size_t)bi * DD);
#pragma unroll
            for (int dq = 0; dq < 8; ++dq) {
                float4 v = cp[ug * 8 + dq];
                int d = ug * 32 + dq * 4;
                float e0 = __fsub_rn(a_t[d + 0][urow], v.x); a_t[d + 0][urow] = e0;
                float e1 = __fsub_rn(a_t[d + 1][urow], v.y); a_t[d + 1][urow] = e1;
                float e2 = __fsub_rn(a_t[d + 2][urow], v.z); a_t[d + 2][urow] = e2;
                float e3 = __fsub_rn(a_t[d + 3][urow], v.w); a_t[d + 3][urow] = e3;
                loss_acc += e0 * e0 + e1 * e1 + e2 * e2 + e3 * e3;
            }
        }
    }
    __syncthreads();

    // ---- outputs ----
    {
        int row = tid >> 3, s2 = tid & 7;
        out[2 + (size_t)(base + row) * KST + s2] = (float)idxhist[s2][row];
    }
    float* q = out + 2 + (size_t)NROWS * KST;
    for (int i = tid; i < ROWS * DD / 4; i += 256) {
        int row = i >> 6, dq = i & 63, d = dq * 4;
        float4 xv = ((const float4*)(x + (size_t)(base + row) * DD))[dq];
        float4 o;
        o.x = xv.x - a_t[d + 0][row];
        o.y = xv.y - a_t[d + 1][row];
        o.z = xv.z - a_t[d + 2][row];
        o.w = xv.w - a_t[d + 3][row];
        ((float4*)(q + (size_t)(base + row) * DD))[dq] = o;
    }
#pragma unroll
    for (int off = 32; off >= 1; off >>= 1) loss_acc += __shfl_down(loss_acc, off, 64);
    if ((tid & 63) == 0) wred[tid >> 6] = loss_acc;
    __syncthreads();
    if (tid == 0) {
        float t = wred[0] + wred[1] + wred[2] + wred[3];
        t *= (1.f / ((float)NROWS * (float)DD));
        atomicAdd(out + 0, t);
        atomicAdd(out + 1, t);
    }
}

// ---------------------------------------------------------------------------
extern "C" void kernel_launch(void* const* d_in, const int* in_sizes, int n_in,
                              void* d_out, int out_size, void* d_ws, size_t ws_size,
                              hipStream_t stream) {
    const float* x   = (const float*)d_in[0];   // [16,2048,256] fp32
    const float* cbs = (const float*)d_in[1];   // [8,1024,256] fp32
    float* out = (float*)d_out;
    float* n32 = (float*)d_ws;                  // 8192 floats

    hipMemsetAsync(d_out, 0, 2 * sizeof(float), stream);
    norms_kernel<<<32, 256, 0, stream>>>(cbs, n32);
    rvq_kernel<<<NROWS / ROWS, 256, 0, stream>>>(x, cbs, n32, out);
}

// Round 9
// 3667.002 us; speedup vs baseline: 1.5291x; 1.5291x over previous
//
#include <hip/hip_runtime.h>

// Problem constants (B,S,D=16,2048,256; K codebooks=8, CD=1024)
#define DD    256
#define KST   8
#define CDN   1024
#define NROWS 32768          // B*S
#define ROWS  32             // rows (tokens) per block
#define NT    128            // codeword tile per sweep
#define KC    16             // k-chunk staged in LDS (double-buffered)
#define NCH   (DD / KC)      // 16 chunks per jb tile
#define TCH   (8 * NCH)      // 128 chunks per stage (8 jb tiles)
#define AST   33             // a_t row stride (32+1 pad)
#define BST   66             // b tile col stride (64+2 pad -> 2-way banks)

__device__ __forceinline__ bool better(float a, int ja, float b, int jb_) {
    return (a < b) || (a == b && ja < jb_);
}

// ---------------------------------------------------------------------------
// numpy AVX512 pairwise sum-of-squares over 256 values (bit-emulated):
// two 128-blocks; per block 8 vectors of 16 lanes, per-lane tree
// ((v0+v1)+(v2+v3))+((v4+v5)+(v6+v7)), then _mm512_reduce_add halving tree,
// then block0+block1. All roundings explicit.
template <typename F>
__device__ __forceinline__ float np_sumsq_256(F ld) {
    float Sv = 0.f;
#pragma unroll
    for (int blk = 0; blk < 2; ++blk) {
        const int o = blk * 128;
        float w[16];
#pragma unroll
        for (int l = 0; l < 16; ++l) {
            float v[8];
#pragma unroll
            for (int j = 0; j < 8; ++j) {
                float xv = ld(o + 16 * j + l);
                v[j] = __fmul_rn(xv, xv);
            }
            float a01 = __fadd_rn(v[0], v[1]);
            float a23 = __fadd_rn(v[2], v[3]);
            float a45 = __fadd_rn(v[4], v[5]);
            float a67 = __fadd_rn(v[6], v[7]);
            w[l] = __fadd_rn(__fadd_rn(a01, a23), __fadd_rn(a45, a67));
        }
        float t8[8];
#pragma unroll
        for (int l = 0; l < 8; ++l) t8[l] = __fadd_rn(w[l], w[l + 8]);
        float t4[4];
#pragma unroll
        for (int l = 0; l < 4; ++l) t4[l] = __fadd_rn(t8[l], t8[l + 4]);
        float t2_0 = __fadd_rn(t4[0], t4[2]);
        float t2_1 = __fadd_rn(t4[1], t4[3]);
        float bs = __fadd_rn(t2_0, t2_1);
        Sv = (blk == 0) ? bs : __fadd_rn(Sv, bs);
    }
    return Sv;
}

// ---------------------------------------------------------------------------
__global__ __launch_bounds__(256) void norms_kernel(const float* __restrict__ cb,
                                                    float* __restrict__ n32) {
    int j = blockIdx.x * 256 + threadIdx.x;   // 0..8191
    const float* p = cb + (size_t)j * DD;
    n32[j] = np_sumsq_256([&](int i) { return p[i]; });
}

// ---------------------------------------------------------------------------
__device__ __forceinline__ void st_chunk(float (*bb)[KC][BST], int li, float4 v) {
    int col = li >> 2, g = li & 3, h = col >> 6, cl = col & 63;
    bb[h][g * 4 + 0][cl] = v.x;
    bb[h][g * 4 + 1][cl] = v.y;
    bb[h][g * 4 + 2][cl] = v.z;
    bb[h][g * 4 + 3][cl] = v.w;
}

// ---------------------------------------------------------------------------
// Fused RVQ — numpy-fp32 emulation (round-8 arithmetic, restructured for
// latency hiding): double-buffered B staging with register prefetch (one
// barrier per chunk, global loads issued a full chunk ahead), 2-way-max LDS
// bank patterns. Per-(row,col) dot chain stays single-accumulator FMA with
// k ascending -> scores bit-identical to round 8.
__global__ __launch_bounds__(256, 3) void rvq_kernel(const float* __restrict__ x,
                                                     const float* __restrict__ cbs,
                                                     const float* __restrict__ n32,
                                                     float* __restrict__ out) {
    __shared__ float a_t[DD][AST];        // residual, transposed: a_t[d][row]
    __shared__ float btb[2][2][KC][BST];  // double-buffered B tile halves
    __shared__ float rowS[ROWS];          // np-AVX512 sum(res*res) per row
    __shared__ int   rowidx[ROWS];
    __shared__ int   idxhist[KST][ROWS];
    __shared__ float wred[4];

    const int tid  = threadIdx.x;
    const int base = blockIdx.x * ROWS;
    const int tx   = tid & 15;            // GEMM col-group
    const int ty   = tid >> 4;            // GEMM row-group (2 rows)
    const int row0 = ty * 2;
    const int urow = tid & 31;            // update row (bank-friendly remap)
    const int ug   = tid >> 5;            // owned 32-dim segment

    for (int i = tid; i < ROWS * DD / 4; i += 256) {
        int row = i >> 6;
        int dq  = i & 63;
        float4 v = ((const float4*)(x + (size_t)(base + row) * DD))[dq];
        int d = dq * 4;
        a_t[d + 0][row] = v.x; a_t[d + 1][row] = v.y;
        a_t[d + 2][row] = v.z; a_t[d + 3][row] = v.w;
    }

    float loss_acc = 0.f;

    for (int s = 0; s < KST; ++s) {
        const float* cb = cbs + (size_t)s * CDN * DD;
        const float* nr = n32 + s * CDN;
        __syncthreads();                  // a_t ready (init load / prev update)

        // np-AVX512 S = sum(res*res) per row; one thread per row
        if (tid < ROWS) {
            int row = tid;
            rowS[row] = np_sumsq_256([&](int i) { return a_t[i][row]; });
        }
        __syncthreads();

        float rb[2]  = {3.4e38f, 3.4e38f};
        int   rjx[2] = {0x7ffffff, 0x7ffffff};
        float acc[2][8];
        float4 nx0, nx1;
        const int li0 = tid, li1 = tid + 256;

        // prestore chunk 0 into buffer 0
        nx0 = *(const float4*)(cb + (size_t)(li0 >> 2) * DD + (li0 & 3) * 4);
        nx1 = *(const float4*)(cb + (size_t)(li1 >> 2) * DD + (li1 & 3) * 4);
        st_chunk(btb[0], li0, nx0);
        st_chunk(btb[0], li1, nx1);

        for (int t = 0; t < TCH; ++t) {
            const int buf = t & 1;
            if (t + 1 < TCH) {            // prefetch next chunk (global->regs)
                int jb2 = ((t + 1) >> 4) * NT, kk2 = ((t + 1) & 15) * KC;
                nx0 = *(const float4*)(cb + (size_t)(jb2 + (li0 >> 2)) * DD + kk2 + (li0 & 3) * 4);
                nx1 = *(const float4*)(cb + (size_t)(jb2 + (li1 >> 2)) * DD + kk2 + (li1 & 3) * 4);
            }
            __syncthreads();              // btb[buf] writes (from iter t-1) visible

            const int jb = (t >> 4) * NT, kk = (t & 15) * KC;
            if ((t & 15) == 0) {
#pragma unroll
                for (int r = 0; r < 2; ++r)
#pragma unroll
                    for (int c = 0; c < 8; ++c) acc[r][c] = 0.f;
            }
            const float (*bb)[KC][BST] = btb[buf];
#pragma unroll
            for (int k = 0; k < KC; ++k) {
                float a0 = a_t[kk + k][row0];
                float a1 = a_t[kk + k][row0 + 1];
                float b0[4], b1[4];
#pragma unroll
                for (int c = 0; c < 4; ++c) {
                    b0[c] = bb[0][k][tx * 4 + c];
                    b1[c] = bb[1][k][tx * 4 + c];
                }
#pragma unroll
                for (int c = 0; c < 4; ++c) {
                    acc[0][c]     = __builtin_fmaf(a0, b0[c], acc[0][c]);
                    acc[0][4 + c] = __builtin_fmaf(a0, b1[c], acc[0][4 + c]);
                    acc[1][c]     = __builtin_fmaf(a1, b0[c], acc[1][c]);
                    acc[1][4 + c] = __builtin_fmaf(a1, b1[c], acc[1][4 + c]);
                }
            }
            if (t + 1 < TCH) {            // stage prefetched chunk into other buffer
                st_chunk(btb[buf ^ 1], li0, nx0);
                st_chunk(btb[buf ^ 1], li1, nx1);
            }
            if ((t & 15) == 15) {         // np-composed score + argmin for this jb
#pragma unroll
                for (int r = 0; r < 2; ++r) {
                    float Srow = rowS[row0 + r];
                    float t1 = 3.4e38f; int u1 = 0x7ffffff;
#pragma unroll
                    for (int h = 0; h < 2; ++h)
#pragma unroll
                        for (int c = 0; c < 4; ++c) {
                            int j = jb + h * 64 + tx * 4 + c;
                            float m2 = __fmul_rn(2.f, acc[r][h * 4 + c]);
                            float sc = __fadd_rn(__fsub_rn(Srow, m2), nr[j]);
                            if (better(sc, j, t1, u1)) { t1 = sc; u1 = j; }
                        }
#pragma unroll
                    for (int off = 8; off >= 1; off >>= 1) {
                        float ob = __shfl_xor(t1, off, 16);
                        int   oj = __shfl_xor(u1, off, 16);
                        if (better(ob, oj, t1, u1)) { t1 = ob; u1 = oj; }
                    }
                    if (tx == 0 && better(t1, u1, rb[r], rjx[r])) { rb[r] = t1; rjx[r] = u1; }
                }
            }
        }
        if (tx == 0) {
#pragma unroll
            for (int r = 0; r < 2; ++r) {
                rowidx[row0 + r] = rjx[r];
                idxhist[s][row0 + r] = rjx[r];
            }
        }
        __syncthreads();

        // residual update + loss (elementwise fp32; banks 2-way via remap)
        {
            int bi = rowidx[urow];
            const float4* cp = (const float4*)(cb + (size_t)bi * DD + ug * 32);
#pragma unroll
            for (int dq = 0; dq < 8; ++dq) {
                float4 v = cp[dq];
                int d = ug * 32 + dq * 4;
                float e0 = __fsub_rn(a_t[d + 0][urow], v.x); a_t[d + 0][urow] = e0;
                float e1 = __fsub_rn(a_t[d + 1][urow], v.y); a_t[d + 1][urow] = e1;
                float e2 = __fsub_rn(a_t[d + 2][urow], v.z); a_t[d + 2][urow] = e2;
                float e3 = __fsub_rn(a_t[d + 3][urow], v.w); a_t[d + 3][urow] = e3;
                loss_acc += e0 * e0 + e1 * e1 + e2 * e2 + e3 * e3;
            }
        }
    }
    __syncthreads();

    // ---- outputs ----
    {
        int row = tid >> 3, s2 = tid & 7;
        out[2 + (size_t)(base + row) * KST + s2] = (float)idxhist[s2][row];
    }
    float* q = out + 2 + (size_t)NROWS * KST;
    for (int i = tid; i < ROWS * DD / 4; i += 256) {
        int row = i >> 6, dq = i & 63, d = dq * 4;
        float4 xv = ((const float4*)(x + (size_t)(base + row) * DD))[dq];
        float4 o;
        o.x = xv.x - a_t[d + 0][row];
        o.y = xv.y - a_t[d + 1][row];
        o.z = xv.z - a_t[d + 2][row];
        o.w = xv.w - a_t[d + 3][row];
        ((float4*)(q + (size_t)(base + row) * DD))[dq] = o;
    }
#pragma unroll
    for (int off = 32; off >= 1; off >>= 1) loss_acc += __shfl_down(loss_acc, off, 64);
    if ((tid & 63) == 0) wred[tid >> 6] = loss_acc;
    __syncthreads();
    if (tid == 0) {
        float t = wred[0] + wred[1] + wred[2] + wred[3];
        t *= (1.f / ((float)NROWS * (float)DD));
        atomicAdd(out + 0, t);
        atomicAdd(out + 1, t);
    }
}

// ---------------------------------------------------------------------------
extern "C" void kernel_launch(void* const* d_in, const int* in_sizes, int n_in,
                              void* d_out, int out_size, void* d_ws, size_t ws_size,
                              hipStream_t stream) {
    const float* x   = (const float*)d_in[0];   // [16,2048,256] fp32
    const float* cbs = (const float*)d_in[1];   // [8,1024,256] fp32
    float* out = (float*)d_out;
    float* n32 = (float*)d_ws;                  // 8192 floats

    hipMemsetAsync(d_out, 0, 2 * sizeof(float), stream);
    norms_kernel<<<32, 256, 0, stream>>>(cbs, n32);
    rvq_kernel<<<NROWS / ROWS, 256, 0, stream>>>(x, cbs, n32, out);
}